// Round 4
// baseline (442.507 us; speedup 1.0000x reference)
//
#include <hip/hip_runtime.h>

#define AREA 2304
#define CH 128
#define C2 64
#define NKT 36  // 2304/64

typedef __attribute__((ext_vector_type(8))) short short8v;
typedef __attribute__((ext_vector_type(4))) short short4v;
typedef __attribute__((ext_vector_type(16))) float f32x16;

__device__ __forceinline__ unsigned short f2bf(float f) {
  union { float f; unsigned u; } a; a.f = f;
  unsigned r = a.u + 0x7fffu + ((a.u >> 16) & 1u);  // RNE
  return (unsigned short)(r >> 16);
}

// ---- projections: Q,K -> [pix][64] bf16 ; V -> [64][pix] bf16 (d-major) ----
// Q is pre-scaled by 0.125*log2(e) so attention scores are in exp2 units.
__global__ __launch_bounds__(256) void proj_kernel(
    const float* __restrict__ povs,
    const float* __restrict__ Wq, const float* __restrict__ bq,
    const float* __restrict__ Wk, const float* __restrict__ bk,
    const float* __restrict__ Wv, const float* __restrict__ bv,
    const int* __restrict__ basep,
    unsigned short* __restrict__ Qb, unsigned short* __restrict__ Kb,
    unsigned short* __restrict__ Vtb) {
  __shared__ unsigned short lv[C2 * 258];  // V repack buffer (padded pitch)
  int z = blockIdx.z;   // 0=Q, 1=K, 2=V
  int img = blockIdx.y; // Q: b (0..7, guard >=8); K/V: oi*8+b (0..23)
  if (z == 0 && img >= 8) return;
  int base = *basep;
  int t = threadIdx.x;
  int pix0 = blockIdx.x * 256;
  int p = pix0 + t;
  const float* W; const float* bias; int vb; float scale;
  if (z == 0) { W = Wq; bias = bq; vb = base * 8 + img; scale = 0.18033688011112042f; }
  else {
    int b = img & 7, oi = img >> 3;
    int v = oi + (oi >= base ? 1 : 0);  // others[] mapping
    vb = v * 8 + b;
    if (z == 1) { W = Wk; bias = bk; } else { W = Wv; bias = bv; }
    scale = 1.0f;
  }
  const float* X = povs + (size_t)vb * CH * AREA;  // [c][p]
  float acc[C2];
  #pragma unroll
  for (int d = 0; d < C2; d++) acc[d] = bias[d];
  for (int cc = 0; cc < CH; cc += 16) {
    float xv[16];
    #pragma unroll
    for (int i = 0; i < 16; i++) xv[i] = X[(size_t)(cc + i) * AREA + p];
    #pragma unroll
    for (int d = 0; d < C2; d++) {
      float a = acc[d];
      #pragma unroll
      for (int i = 0; i < 16; i++) a = fmaf(xv[i], W[d * CH + cc + i], a);
      acc[d] = a;
    }
  }
  if (z <= 1) {
    // row-major [p][64]: per-thread contiguous 128B, 8x b128 stores
    unsigned short* outp = (z == 0 ? Qb : Kb) + (size_t)img * AREA * C2 + (size_t)p * C2;
    #pragma unroll
    for (int c = 0; c < 8; c++) {
      short8v pk;
      #pragma unroll
      for (int j = 0; j < 8; j++) pk[j] = (short)f2bf(acc[c * 8 + j] * scale);
      *(short8v*)(outp + c * 8) = pk;
    }
  } else {
    // V: transpose via LDS so global stores are coalesced [d][p]
    #pragma unroll
    for (int d = 0; d < C2; d++) lv[d * 258 + t] = f2bf(acc[d] * scale);
    __syncthreads();
    unsigned int* ob = (unsigned int*)(Vtb + (size_t)img * C2 * AREA);
    #pragma unroll
    for (int rep = 0; rep < 32; rep++) {
      int idx = rep * 256 + t;
      int d = idx >> 7, pc = idx & 127;
      unsigned int val = *(unsigned int*)&lv[d * 258 + 2 * pc];
      ob[((size_t)d * AREA + pix0) / 2 + pc] = val;
    }
  }
}

// ---- xbar[b][c] = mean_p Xb[b][c][p] ----
__global__ __launch_bounds__(256) void xbar_kernel(
    const float* __restrict__ povs, const int* __restrict__ basep,
    float* __restrict__ xbar) {
  int row = blockIdx.x * 4 + (threadIdx.x >> 6);  // b*128 + c, 1024 rows
  int lane = threadIdx.x & 63;
  int base = *basep;
  const float* X = povs + (size_t)base * 8 * CH * AREA + (size_t)row * AREA;
  float s = 0.f;
  for (int i = lane; i < AREA; i += 64) s += X[i];
  #pragma unroll
  for (int m = 1; m < 64; m <<= 1) s += __shfl_xor(s, m);
  if (lane == 0) xbar[row] = s * (1.0f / AREA);
}

// ---- flash attention, swapped-operand 32x32x16 MFMA, q-pooled output ----
__global__ __launch_bounds__(256) void attn_kernel(
    const unsigned short* __restrict__ Qb, const unsigned short* __restrict__ Kb,
    const unsigned short* __restrict__ Vtb, float* __restrict__ Zbar) {
  __shared__ __align__(16) char plds[4][4096];  // per-wave P buffer, XOR-swizzled
  int hd = blockIdx.y;            // 0..23 = oi*8+b
  int b = hd & 7;
  int wid = threadIdx.x >> 6, lane = threadIdx.x & 63;
  int lq = lane & 31, h = lane >> 5;
  const unsigned short* Qp = Qb + (size_t)b * AREA * C2;
  const unsigned short* Kp = Kb + (size_t)hd * AREA * C2;
  const unsigned short* Vp = Vtb + (size_t)hd * C2 * AREA;
  char* myp = plds[wid];
  int q0 = blockIdx.x * 128 + wid * 32;

  // Q fragments (B-operand): lane holds Q[q0+lq][16c+8h .. +8]
  short8v qf[4];
  #pragma unroll
  for (int c = 0; c < 4; c++)
    qf[c] = *(const short8v*)(Qp + (size_t)(q0 + lq) * C2 + c * 16 + h * 8);

  f32x16 zacc0 = (f32x16)(0.0f), zacc1 = (f32x16)(0.0f);
  float m_run = -__builtin_inff(), l_run = 0.f;

  for (int kt = 0; kt < NKT; kt++) {
    int kb = kt * 64;
    // St[k][q] = sum_d K[k][d]*Q[q][d]  (A=K frag, B=Q frag)
    f32x16 st0 = (f32x16)(0.0f), st1 = (f32x16)(0.0f);
    #pragma unroll
    for (int c = 0; c < 4; c++) {
      short8v ka0 = *(const short8v*)(Kp + (size_t)(kb + lq) * C2 + c * 16 + h * 8);
      short8v ka1 = *(const short8v*)(Kp + (size_t)(kb + 32 + lq) * C2 + c * 16 + h * 8);
      st0 = __builtin_amdgcn_mfma_f32_32x32x16_bf16(ka0, qf[c], st0, 0, 0, 0);
      st1 = __builtin_amdgcn_mfma_f32_32x32x16_bf16(ka1, qf[c], st1, 0, 0, 0);
    }
    // issue V fragment loads early (consumed after softmax)
    short8v vf0[4], vf1[4];
    #pragma unroll
    for (int s = 0; s < 4; s++) {
      vf0[s] = *(const short8v*)(Vp + (size_t)lq * AREA + kb + 16 * s + 8 * h);
      vf1[s] = *(const short8v*)(Vp + (size_t)(32 + lq) * AREA + kb + 16 * s + 8 * h);
    }
    // ---- online softmax in exp2 units; lane owns q = lq (both halves identical state)
    float pmax = st0[0];
    #pragma unroll
    for (int i = 1; i < 16; i++) pmax = fmaxf(pmax, st0[i]);
    #pragma unroll
    for (int i = 0; i < 16; i++) pmax = fmaxf(pmax, st1[i]);
    pmax = fmaxf(pmax, __shfl_xor(pmax, 32));  // other 32 k of the tile
    if (!__all(pmax - m_run <= 12.0f)) {       // deferred-max rescale (fires at kt=0)
      float nm = fmaxf(m_run, pmax);
      float al = exp2f(m_run - nm);
      l_run *= al;
      #pragma unroll
      for (int i = 0; i < 16; i++) { zacc0[i] *= al; zacc1[i] *= al; }
      m_run = nm;
    }
    float pv[32]; float ts = 0.f;
    #pragma unroll
    for (int i = 0; i < 16; i++) { pv[i] = exp2f(st0[i] - m_run); ts += pv[i]; }
    #pragma unroll
    for (int i = 0; i < 16; i++) { pv[16 + i] = exp2f(st1[i] - m_run); ts += pv[16 + i]; }
    ts += __shfl_xor(ts, 32);
    l_run += ts;
    // ---- pack P to LDS: reg i of tile mt holds k = 32mt + 8*(i>>2) + 4h + (i&3), col q=lq
    #pragma unroll
    for (int mt = 0; mt < 2; mt++)
      #pragma unroll
      for (int rq = 0; rq < 4; rq++) {
        short4v pk;
        #pragma unroll
        for (int j = 0; j < 4; j++) pk[j] = (short)f2bf(pv[mt * 16 + rq * 4 + j]);
        int kbyte = (32 * mt + 8 * rq + 4 * h) * 2;
        *(short4v*)(myp + lq * 128 + (kbyte ^ ((lq & 7) << 4))) = pk;
      }
    // ---- Zt[d][q] += V[d][k] * P[k][q]  (A=V frag, B=P frag from LDS)
    #pragma unroll
    for (int s = 0; s < 4; s++) {
      int rb = (32 * s + 16 * h) ^ ((lq & 7) << 4);
      short8v pf = *(const short8v*)(myp + lq * 128 + rb);
      zacc0 = __builtin_amdgcn_mfma_f32_32x32x16_bf16(vf0[s], pf, zacc0, 0, 0, 0);
      zacc1 = __builtin_amdgcn_mfma_f32_32x32x16_bf16(vf1[s], pf, zacc1, 0, 0, 0);
    }
  }
  // normalize rows (lane-local: col q = lq) and pool over q
  float inv = 1.0f / l_run;
  #pragma unroll
  for (int i = 0; i < 16; i++) {
    float a0 = zacc0[i] * inv, a1 = zacc1[i] * inv;
    #pragma unroll
    for (int m = 1; m < 32; m <<= 1) { a0 += __shfl_xor(a0, m); a1 += __shfl_xor(a1, m); }
    zacc0[i] = a0; zacc1[i] = a1;
  }
  if (lq == 0) {
    #pragma unroll
    for (int i = 0; i < 16; i++) {
      int drow = (i & 3) + 8 * (i >> 2) + 4 * h;
      atomicAdd(&Zbar[b * C2 + drow], zacc0[i]);
      atomicAdd(&Zbar[b * C2 + 32 + drow], zacc1[i]);
    }
  }
}

// ---- epilogue: pooled = (xbar + Wz*Zbar/AREA + 3*bz)/4 ; out = pooled@Wfc^T + bfc
__global__ __launch_bounds__(128) void final_kernel(
    const float* __restrict__ xbar, const float* __restrict__ Zbar,
    const float* __restrict__ Wz, const float* __restrict__ bz,
    const float* __restrict__ Wfc, const float* __restrict__ bfc,
    float* __restrict__ out) {
  int b = blockIdx.x, t = threadIdx.x;  // t = channel c (then output j)
  __shared__ float pld[CH];
  float zd = 0.f;
  #pragma unroll
  for (int d = 0; d < C2; d++) zd = fmaf(Wz[t * C2 + d], Zbar[b * C2 + d], zd);
  pld[t] = (xbar[b * CH + t] + zd * (1.0f / AREA) + 3.0f * bz[t]) * 0.25f;
  __syncthreads();
  float a = 0.f;
  #pragma unroll
  for (int c = 0; c < CH; c++) a = fmaf(Wfc[t * CH + c], pld[c], a);
  out[b * CH + t] = a + bfc[t];
}

extern "C" void kernel_launch(void* const* d_in, const int* in_sizes, int n_in,
                              void* d_out, int out_size, void* d_ws, size_t ws_size,
                              hipStream_t stream) {
  const float* povs = (const float*)d_in[0];
  const float* Wq  = (const float*)d_in[1];
  const float* bq  = (const float*)d_in[2];
  const float* Wk  = (const float*)d_in[3];
  const float* bk  = (const float*)d_in[4];
  const float* Wv  = (const float*)d_in[5];
  const float* bv  = (const float*)d_in[6];
  const float* Wz  = (const float*)d_in[7];
  const float* bz  = (const float*)d_in[8];
  const float* Wfc = (const float*)d_in[9];
  const float* bfc = (const float*)d_in[10];
  const int* basep = (const int*)d_in[11];

  char* ws = (char*)d_ws;
  unsigned short* Qb  = (unsigned short*)ws;                       // 8*2304*64*2   = 2359296
  unsigned short* Kb  = (unsigned short*)(ws + 2359296);           // 24*2304*64*2  = 7077888
  unsigned short* Vtb = (unsigned short*)(ws + 2359296 + 7077888); // 24*64*2304*2  = 7077888
  float* Zbar = (float*)(ws + 2359296 + 7077888 * 2);              // 8*64*4 = 2048
  float* xbar = (float*)(ws + 2359296 + 7077888 * 2 + 2048);       // 8*128*4 = 4096

  hipMemsetAsync(Zbar, 0, 8 * C2 * sizeof(float), stream);
  proj_kernel<<<dim3(9, 24, 3), dim3(256), 0, stream>>>(
      povs, Wq, bq, Wk, bk, Wv, bv, basep, Qb, Kb, Vtb);
  xbar_kernel<<<dim3(256), dim3(256), 0, stream>>>(povs, basep, xbar);
  attn_kernel<<<dim3(18, 24), dim3(256), 0, stream>>>(Qb, Kb, Vtb, Zbar);
  final_kernel<<<dim3(8), dim3(128), 0, stream>>>(xbar, Zbar, Wz, bz, Wfc, bfc, (float*)d_out);
}